// Round 3
// baseline (11546.843 us; speedup 1.0000x reference)
//
#include <hip/hip_runtime.h>

typedef unsigned short u16;
typedef __attribute__((ext_vector_type(8))) short bf16x8;
typedef __attribute__((ext_vector_type(4))) float f32x4;
typedef __attribute__((ext_vector_type(2))) float f32x2;

#define QN    2048
#define BSZ   128
#define TMAXK 128
#define STEPF 0.01f
#define NEWTON_ITERS 46
#define NBLK  256

__device__ __forceinline__ u16 f2bf(float f){
  unsigned u = __float_as_uint(f);
  u += 0x7fffu + ((u >> 16) & 1u);          // round-to-nearest-even
  return (u16)(u >> 16);
}
__device__ __forceinline__ float bf2f(u16 h){
  return __uint_as_float(((unsigned)h) << 16);
}

// ============================ preprocessing ============================

// alpha[q] = ||P_q||_1 * ||P_q||_inf  >= sigma_max(P_q)^2
__global__ __launch_bounds__(256) void alpha_k(const float* __restrict__ P, float* __restrict__ alpha){
  int q = blockIdx.x, i = threadIdx.x;
  const float* Pb = P + (size_t)(q << 8) * QN + (q << 8);
  float rs = 0.f, cs = 0.f;
  for (int c = 0; c < 256; ++c){
    rs += fabsf(Pb[(size_t)i * QN + c]);
    cs += fabsf(Pb[(size_t)c * QN + i]);
  }
  __shared__ float red[256];
  red[i] = rs; __syncthreads();
  for (int o = 128; o > 0; o >>= 1){ if (i < o) red[i] = fmaxf(red[i], red[i+o]); __syncthreads(); }
  float mr = red[0];
  __syncthreads();
  red[i] = cs; __syncthreads();
  for (int o = 128; o > 0; o >>= 1){ if (i < o) red[i] = fmaxf(red[i], red[i+o]); __syncthreads(); }
  if (i == 0) alpha[q] = mr * red[0];
}

// V0 = P_q^T / alpha[q]
__global__ __launch_bounds__(256) void initV_k(const float* __restrict__ P, const float* __restrict__ alpha, float* __restrict__ V){
  int idx = blockIdx.x * 256 + threadIdx.x;
  int q = idx >> 16, rc = idx & 65535;
  int r = rc >> 8, c = rc & 255;
  V[idx] = P[(size_t)((q << 8) + c) * QN + (q << 8) + r] / alpha[q];
}

// T[q] = P_q @ V[q]
__global__ __launch_bounds__(256) void newton_T_k(const float* __restrict__ P, const float* __restrict__ Vin, float* __restrict__ Tm){
  int q = blockIdx.x >> 4;
  int tl = blockIdx.x & 15;
  int rb = (tl >> 2) << 6, cb = (tl & 3) << 6;
  const float* Ab = P + (size_t)(q << 8) * QN + (q << 8);
  const float* Bb = Vin + (q << 16);
  __shared__ float Asm[16][68];
  __shared__ float Bsm[16][68];
  int tid = threadIdx.x, ty = tid >> 4, tx = tid & 15;
  float acc[4][4];
#pragma unroll
  for (int i = 0; i < 4; i++)
#pragma unroll
    for (int j = 0; j < 4; j++) acc[i][j] = 0.f;
  int ar = tid >> 2, ak = (tid & 3) << 2;
  int bc = tid & 63, bk = tid >> 6;
  for (int kb = 0; kb < 256; kb += 16){
    f32x4 av = *(const f32x4*)(Ab + (size_t)(rb + ar) * QN + kb + ak);
    float b0 = Bb[(size_t)(kb + bk     ) * 256 + cb + bc];
    float b1 = Bb[(size_t)(kb + bk +  4) * 256 + cb + bc];
    float b2 = Bb[(size_t)(kb + bk +  8) * 256 + cb + bc];
    float b3 = Bb[(size_t)(kb + bk + 12) * 256 + cb + bc];
    __syncthreads();
    Asm[ak+0][ar] = av.x; Asm[ak+1][ar] = av.y; Asm[ak+2][ar] = av.z; Asm[ak+3][ar] = av.w;
    Bsm[bk   ][bc] = b0;  Bsm[bk+ 4][bc] = b1;  Bsm[bk+ 8][bc] = b2;  Bsm[bk+12][bc] = b3;
    __syncthreads();
#pragma unroll
    for (int kk = 0; kk < 16; kk++){
      f32x4 a = *(const f32x4*)&Asm[kk][ty << 2];
      f32x4 b = *(const f32x4*)&Bsm[kk][tx << 2];
#pragma unroll
      for (int i = 0; i < 4; i++)
#pragma unroll
        for (int j = 0; j < 4; j++) acc[i][j] += a[i] * b[j];
    }
  }
  float* Ob = Tm + (q << 16);
#pragma unroll
  for (int i = 0; i < 4; i++){
    f32x4 o; o.x = acc[i][0]; o.y = acc[i][1]; o.z = acc[i][2]; o.w = acc[i][3];
    *(f32x4*)(Ob + (size_t)(rb + (ty << 2) + i) * 256 + cb + (tx << 2)) = o;
  }
}

// Vout[q] = 2*Vin[q] - Vin[q] @ T[q]
__global__ __launch_bounds__(256) void newton_V_k(const float* __restrict__ Vin, const float* __restrict__ Tm, float* __restrict__ Vout){
  int q = blockIdx.x >> 4;
  int tl = blockIdx.x & 15;
  int rb = (tl >> 2) << 6, cb = (tl & 3) << 6;
  const float* Ab = Vin + (q << 16);
  const float* Bb = Tm + (q << 16);
  __shared__ float Asm[16][68];
  __shared__ float Bsm[16][68];
  int tid = threadIdx.x, ty = tid >> 4, tx = tid & 15;
  float acc[4][4];
#pragma unroll
  for (int i = 0; i < 4; i++)
#pragma unroll
    for (int j = 0; j < 4; j++) acc[i][j] = 0.f;
  int ar = tid >> 2, ak = (tid & 3) << 2;
  int bc = tid & 63, bk = tid >> 6;
  for (int kb = 0; kb < 256; kb += 16){
    f32x4 av = *(const f32x4*)(Ab + (size_t)(rb + ar) * 256 + kb + ak);
    float b0 = Bb[(size_t)(kb + bk     ) * 256 + cb + bc];
    float b1 = Bb[(size_t)(kb + bk +  4) * 256 + cb + bc];
    float b2 = Bb[(size_t)(kb + bk +  8) * 256 + cb + bc];
    float b3 = Bb[(size_t)(kb + bk + 12) * 256 + cb + bc];
    __syncthreads();
    Asm[ak+0][ar] = av.x; Asm[ak+1][ar] = av.y; Asm[ak+2][ar] = av.z; Asm[ak+3][ar] = av.w;
    Bsm[bk   ][bc] = b0;  Bsm[bk+ 4][bc] = b1;  Bsm[bk+ 8][bc] = b2;  Bsm[bk+12][bc] = b3;
    __syncthreads();
#pragma unroll
    for (int kk = 0; kk < 16; kk++){
      f32x4 a = *(const f32x4*)&Asm[kk][ty << 2];
      f32x4 b = *(const f32x4*)&Bsm[kk][tx << 2];
#pragma unroll
      for (int i = 0; i < 4; i++)
#pragma unroll
        for (int j = 0; j < 4; j++) acc[i][j] += a[i] * b[j];
    }
  }
  float* Ob = Vout + (q << 16);
#pragma unroll
  for (int i = 0; i < 4; i++){
    f32x4 vo = *(const f32x4*)(Ab + (size_t)(rb + (ty << 2) + i) * 256 + cb + (tx << 2));
    f32x4 o;
    o.x = 2.f*vo.x - acc[i][0]; o.y = 2.f*vo.y - acc[i][1];
    o.z = 2.f*vo.z - acc[i][2]; o.w = 2.f*vo.w - acc[i][3];
    *(f32x4*)(Ob + (size_t)(rb + (ty << 2) + i) * 256 + cb + (tx << 2)) = o;
  }
}

// Ymat[:, Bj] = Wm[Bj,:]^T @ P_j
__global__ __launch_bounds__(256) void build_Y_k(const float* __restrict__ W, const float* __restrict__ P, float* __restrict__ Ymat){
  int j  = blockIdx.x >> 7;
  int rt = (blockIdx.x >> 2) & 31;
  int ct = blockIdx.x & 3;
  int rb = rt << 6, cb = ct << 6, jb = j << 8;
  int tid = threadIdx.x, ty = tid >> 4, tx = tid & 15;
  if ((rt >> 2) == j){
#pragma unroll
    for (int i = 0; i < 4; i++){
      f32x4 z = {0.f, 0.f, 0.f, 0.f};
      *(f32x4*)(Ymat + (size_t)(rb + (ty << 2) + i) * QN + jb + cb + (tx << 2)) = z;
    }
    return;
  }
  __shared__ float Asm[16][68];
  __shared__ float Bsm[16][68];
  float acc[4][4];
#pragma unroll
  for (int i = 0; i < 4; i++)
#pragma unroll
    for (int j2 = 0; j2 < 4; j2++) acc[i][j2] = 0.f;
  int sr = tid & 63, sk = tid >> 6;
  for (int kb = 0; kb < 256; kb += 16){
    float a0 = W[(size_t)(jb + kb + sk     ) * QN + rb + sr];
    float a1 = W[(size_t)(jb + kb + sk +  4) * QN + rb + sr];
    float a2 = W[(size_t)(jb + kb + sk +  8) * QN + rb + sr];
    float a3 = W[(size_t)(jb + kb + sk + 12) * QN + rb + sr];
    float b0 = P[(size_t)(jb + kb + sk     ) * QN + jb + cb + sr];
    float b1 = P[(size_t)(jb + kb + sk +  4) * QN + jb + cb + sr];
    float b2 = P[(size_t)(jb + kb + sk +  8) * QN + jb + cb + sr];
    float b3 = P[(size_t)(jb + kb + sk + 12) * QN + jb + cb + sr];
    __syncthreads();
    Asm[sk   ][sr] = a0; Asm[sk+ 4][sr] = a1; Asm[sk+ 8][sr] = a2; Asm[sk+12][sr] = a3;
    Bsm[sk   ][sr] = b0; Bsm[sk+ 4][sr] = b1; Bsm[sk+ 8][sr] = b2; Bsm[sk+12][sr] = b3;
    __syncthreads();
#pragma unroll
    for (int kk = 0; kk < 16; kk++){
      f32x4 a = *(const f32x4*)&Asm[kk][ty << 2];
      f32x4 b = *(const f32x4*)&Bsm[kk][tx << 2];
#pragma unroll
      for (int i = 0; i < 4; i++)
#pragma unroll
        for (int j2 = 0; j2 < 4; j2++) acc[i][j2] += a[i] * b[j2];
    }
  }
#pragma unroll
  for (int i = 0; i < 4; i++){
    f32x4 o; o.x = acc[i][0]; o.y = acc[i][1]; o.z = acc[i][2]; o.w = acc[i][3];
    *(f32x4*)(Ymat + (size_t)(rb + (ty << 2) + i) * QN + jb + cb + (tx << 2)) = o;
  }
}

// Z[Bi,:] = V_i @ Ymat[Bi,:];  M = A + Wm - Z; write bf16 hi/lo into C1/C2
__global__ __launch_bounds__(256) void build_C_k(const float* __restrict__ Vfin, const float* __restrict__ Ymat,
                                                 const float* __restrict__ Ain, const float* __restrict__ W,
                                                 u16* __restrict__ C1, u16* __restrict__ C2){
  int ib = blockIdx.x >> 7;
  int rest = blockIdx.x & 127;
  int rt = rest >> 5, ct = rest & 31;
  int rb = rt << 6, cb = ct << 6;
  const float* Ab = Vfin + (ib << 16);
  __shared__ float Asm[16][68];
  __shared__ float Bsm[16][68];
  int tid = threadIdx.x, ty = tid >> 4, tx = tid & 15;
  float acc[4][4];
#pragma unroll
  for (int i = 0; i < 4; i++)
#pragma unroll
    for (int j = 0; j < 4; j++) acc[i][j] = 0.f;
  int ar = tid >> 2, ak = (tid & 3) << 2;
  int bc = tid & 63, bk = tid >> 6;
  for (int kb = 0; kb < 256; kb += 16){
    f32x4 av = *(const f32x4*)(Ab + (size_t)(rb + ar) * 256 + kb + ak);
    float b0 = Ymat[(size_t)((ib << 8) + kb + bk     ) * QN + cb + bc];
    float b1 = Ymat[(size_t)((ib << 8) + kb + bk +  4) * QN + cb + bc];
    float b2 = Ymat[(size_t)((ib << 8) + kb + bk +  8) * QN + cb + bc];
    float b3 = Ymat[(size_t)((ib << 8) + kb + bk + 12) * QN + cb + bc];
    __syncthreads();
    Asm[ak+0][ar] = av.x; Asm[ak+1][ar] = av.y; Asm[ak+2][ar] = av.z; Asm[ak+3][ar] = av.w;
    Bsm[bk   ][bc] = b0;  Bsm[bk+ 4][bc] = b1;  Bsm[bk+ 8][bc] = b2;  Bsm[bk+12][bc] = b3;
    __syncthreads();
#pragma unroll
    for (int kk = 0; kk < 16; kk++){
      f32x4 a = *(const f32x4*)&Asm[kk][ty << 2];
      f32x4 b = *(const f32x4*)&Bsm[kk][tx << 2];
#pragma unroll
      for (int i = 0; i < 4; i++)
#pragma unroll
        for (int j = 0; j < 4; j++) acc[i][j] += a[i] * b[j];
    }
  }
#pragma unroll
  for (int i = 0; i < 4; i++){
    int row = (ib << 8) + rb + (ty << 2) + i;
#pragma unroll
    for (int j = 0; j < 4; j++){
      int col = cb + (tx << 2) + j;
      float wv = ((row >> 8) == (col >> 8)) ? 0.f : W[(size_t)row * QN + col];
      float m = Ain[(size_t)row * QN + col] + wv - acc[i][j];
      u16 hi = f2bf(m);
      u16 lo = f2bf(m - bf2f(hi));
      C1[((size_t)row << 12) + col] = hi;
      C2[((size_t)row << 12) + col] = lo;
    }
  }
}

// B matrix -> bf16 hi/lo into C1/C2 (cols 2048..4095)
__global__ __launch_bounds__(256) void split_B_k(const float* __restrict__ Bin, u16* __restrict__ C1, u16* __restrict__ C2){
  int idx = blockIdx.x * 256 + threadIdx.x;
  int r = idx >> 11, c = idx & 2047;
  float v = Bin[idx];
  u16 hi = f2bf(v);
  u16 lo = f2bf(v - bf2f(hi));
  C1[((size_t)r << 12) + 2048 + c] = hi;
  C2[((size_t)r << 12) + 2048 + c] = lo;
}

// Yst = [bf16(X0) | bf16(relu X0)]; out[:,0,:] = X0
__global__ __launch_bounds__(256) void init_state_k(const float* __restrict__ X0,
                                                    u16* __restrict__ Yst, float* __restrict__ out){
  int idx = blockIdx.x * 256 + threadIdx.x;
  int bs = idx >> 11, qn = idx & 2047;
  float x = X0[idx];
  Yst[((size_t)bs << 12) + qn] = f2bf(x);
  Yst[((size_t)bs << 12) + 2048 + qn] = f2bf(fmaxf(x, 0.f));
  out[((size_t)bs * TMAXK) * QN + qn] = x;
}

// ============================ persistent main loop ============================

__device__ __forceinline__ void grid_bar(unsigned* cnt, unsigned* gen, unsigned target){
  __syncthreads();
  if (threadIdx.x == 0){
    __threadfence();   // release: flush dirty L2 (device scope)
    unsigned old = __hip_atomic_fetch_add(cnt, 1u, __ATOMIC_ACQ_REL, __HIP_MEMORY_SCOPE_AGENT);
    if (old == (unsigned)(NBLK - 1)){
      __hip_atomic_store(cnt, 0u, __ATOMIC_RELAXED, __HIP_MEMORY_SCOPE_AGENT);
      __hip_atomic_store(gen, target, __ATOMIC_RELEASE, __HIP_MEMORY_SCOPE_AGENT);
    } else {
      while (__hip_atomic_load(gen, __ATOMIC_ACQUIRE, __HIP_MEMORY_SCOPE_AGENT) < target)
        __builtin_amdgcn_s_sleep(2);
    }
    __threadfence();   // acquire: invalidate stale cache lines
  }
  __syncthreads();
}

// 256 blocks (1/CU) x 512 thr. Block b: rowgroup rg=b>>3 (64 rows), k-slice s=b&7 (512 k).
// C1+C2 [64r][512k] resident in LDS (128 KB, XOR-swizzled). State X in registers (2 f32/thread).
// Note: s = b&7 => all blocks on XCD x share k-slice x => per-XCD L2 holds exactly its Y-slice.
__global__ void __launch_bounds__(512, 1) persist_k(
    const u16* __restrict__ C1, const u16* __restrict__ C2,
    u16* __restrict__ Yst, float* __restrict__ part,
    const float* __restrict__ X0, const float* __restrict__ bx,
    float* __restrict__ out, unsigned* cnt, unsigned* gen){
  extern __shared__ char lds[];
  int b = blockIdx.x, tid = threadIdx.x;
  int rg = b >> 3, s = b & 7;
  // ---- stage C panels into LDS once ----
  for (int it = 0; it < 16; ++it){
    int e = it * 512 + tid;                 // [0,8192): 8 bf16 each
    const u16* src = (e < 4096) ? C1 : C2;  // uniform per it
    int el = e & 4095;
    int r = el >> 6;                        // 0..63
    int k8 = (el & 63) << 3;                // 0..504
    bf16x8 v = *(const bf16x8*)(src + ((size_t)((rg << 6) + r) << 12) + (s << 9) + k8);
    int addr = ((e >> 12) << 16) + ((((r << 10) + (k8 << 1))) ^ ((r & 7) << 4));
    *(bf16x8*)(lds + addr) = v;
  }
  __syncthreads();
  // ---- per-thread roles ----
  int w = tid >> 6, l = tid & 63;
  int lo16 = l & 15, hi = l >> 4;
  int m = w & 3, nh = w >> 2;               // wave: rows [m*16,+16), batch [nh*64,+64)
  int row16 = (m << 4) + lo16;
  int abase = ((row16 << 10)) ^ ((row16 & 7) << 4);
  const u16* yb0 = Yst + ((size_t)((nh << 6) + lo16) << 12) + (s << 9) + (hi << 3);
  // update-phase mapping: 2 f32 per thread
  int g = b * 512 + tid;
  int bs_u = g >> 10;
  int row2 = (g & 1023) << 1;
  size_t xbase = ((size_t)bs_u << 11) + row2;
  float b0v = bx[row2], b1v = bx[row2 + 1];
  float x0 = X0[xbase], x1 = X0[xbase + 1];  // state lives in registers
  unsigned bt = 0;
  for (int t = 1; t < TMAXK; ++t){
    // ---- GEMM phase: part[s] += (C1+C2)[64r, 512k] @ Y[:,512k]^T ----
    f32x4 acc[4];
#pragma unroll
    for (int n = 0; n < 4; n++) acc[n] = (f32x4){0.f, 0.f, 0.f, 0.f};
#pragma unroll 4
    for (int ks = 0; ks < 16; ++ks){
      int ba = abase + ((ks << 6) + (hi << 4)) ;
      // note: kb bits don't collide with the XOR bits only when...; recompute safely:
      ba = ((row16 << 10) + ((ks << 6) + (hi << 4))) ^ ((row16 & 7) << 4);
      bf16x8 a1 = *(const bf16x8*)(lds + ba);
      bf16x8 a2 = *(const bf16x8*)(lds + 65536 + ba);
#pragma unroll
      for (int n = 0; n < 4; ++n){
        bf16x8 bf = *(const bf16x8*)(yb0 + ((size_t)n << 16) + (ks << 5));
        acc[n] = __builtin_amdgcn_mfma_f32_16x16x32_bf16(a1, bf, acc[n], 0, 0, 0);
        acc[n] = __builtin_amdgcn_mfma_f32_16x16x32_bf16(a2, bf, acc[n], 0, 0, 0);
      }
    }
#pragma unroll
    for (int n = 0; n < 4; ++n){
      int bs = (nh << 6) + (n << 4) + lo16;
      int row = (rg << 6) + (m << 4) + (hi << 2);
      *(f32x4*)(part + ((size_t)((s << 7) + bs) << 11) + row) = acc[n];
    }
    grid_bar(cnt, gen, ++bt);
    // ---- update phase: X += 0.01*(sum(part) + b); emit out, Yst ----
    float u0 = 0.f, u1 = 0.f;
#pragma unroll
    for (int sl = 0; sl < 8; ++sl){
      const float* pp = part + ((size_t)((sl << 7) + bs_u) << 11) + row2;
      u0 += pp[0]; u1 += pp[1];
    }
    x0 = x0 + STEPF * (u0 + b0v);
    x1 = x1 + STEPF * (u1 + b1v);
    *(f32x2*)(out + ((size_t)((bs_u << 7) + t) << 11) + row2) = (f32x2){x0, x1};
    unsigned hv = (unsigned)f2bf(x0) | ((unsigned)f2bf(x1) << 16);
    unsigned rv = (unsigned)f2bf(fmaxf(x0, 0.f)) | ((unsigned)f2bf(fmaxf(x1, 0.f)) << 16);
    *(unsigned*)(Yst + ((size_t)bs_u << 12) + row2) = hv;
    *(unsigned*)(Yst + ((size_t)bs_u << 12) + 2048 + row2) = rv;
    grid_bar(cnt, gen, ++bt);
  }
}

// ============================ host ============================

extern "C" void kernel_launch(void* const* d_in, const int* in_sizes, int n_in,
                              void* d_out, int out_size, void* d_ws, size_t ws_size,
                              hipStream_t stream){
  (void)in_sizes; (void)n_in; (void)out_size; (void)ws_size;
  const float* X0  = (const float*)d_in[0];
  const float* Ain = (const float*)d_in[1];
  const float* Bin = (const float*)d_in[2];
  const float* Win = (const float*)d_in[3];
  const float* Pin = (const float*)d_in[4];
  const float* bx  = (const float*)d_in[5];
  float* out = (float*)d_out;
  char* ws = (char*)d_ws;
  const size_t MB = 1u << 20;

  u16*     C1    = (u16*)(ws);               // 16 MB [2048][4096] bf16 = [Mh|Bh]
  u16*     C2    = (u16*)(ws + 16*MB);       // 16 MB [Ml|Bl]
  unsigned* barc = (unsigned*)(ws + 32*MB);  // grid barrier count
  unsigned* barg = (unsigned*)(ws + 32*MB + 256); // grid barrier generation
  u16*     Yst   = (u16*)(ws + 33*MB);       // 1 MB  [128][4096] bf16 [X|relu X]
  float*   Ymat  = (float*)(ws + 34*MB);     // 16 MB (preproc)  -- aliased with:
  float*   part  = (float*)(ws + 34*MB);     // 8 MB [8][128][2048] f32 partials (main loop)
  float*   Vb0   = (float*)(ws + 50*MB);     // 2 MB  8x256x256
  float*   Vb1   = (float*)(ws + 52*MB);     // 2 MB
  float*   Tm    = (float*)(ws + 54*MB);     // 2 MB
  float*   alpha = (float*)(ws + 56*MB);     // 32 B

  hipMemsetAsync(ws + 32*MB, 0, 512, stream);   // zero barrier state every launch

  // --- preprocessing: blockwise P^-1 via Newton-Schulz ---
  alpha_k<<<8, 256, 0, stream>>>(Pin, alpha);
  initV_k<<<2048, 256, 0, stream>>>(Pin, alpha, Vb0);
  float* Vc = Vb0; float* Vo = Vb1;
  for (int it = 0; it < NEWTON_ITERS; ++it){
    newton_T_k<<<128, 256, 0, stream>>>(Pin, Vc, Tm);
    newton_V_k<<<128, 256, 0, stream>>>(Vc, Tm, Vo);
    float* tmp = Vc; Vc = Vo; Vo = tmp;
  }
  // --- M = A + Wm - P^-1 Wm^T P, split to bf16 hi/lo; B split too ---
  build_Y_k<<<1024, 256, 0, stream>>>(Win, Pin, Ymat);
  build_C_k<<<1024, 256, 0, stream>>>(Vc, Ymat, Ain, Win, C1, C2);
  split_B_k<<<16384, 256, 0, stream>>>(Bin, C1, C2);
  init_state_k<<<1024, 256, 0, stream>>>(X0, Yst, out);

  // --- 127 sequential steps in one persistent cooperative kernel ---
  hipFuncSetAttribute((const void*)persist_k, hipFuncAttributeMaxDynamicSharedMemorySize, 131072);
  void* kargs[] = {(void*)&C1, (void*)&C2, (void*)&Yst, (void*)&part,
                   (void*)&X0, (void*)&bx, (void*)&out, (void*)&barc, (void*)&barg};
  hipLaunchCooperativeKernel((void*)persist_k, dim3(NBLK), dim3(512), kargs, 131072, stream);
}

// Round 5
// 3482.706 us; speedup vs baseline: 3.3155x; 3.3155x over previous
//
#include <hip/hip_runtime.h>

typedef unsigned short u16;
typedef __attribute__((ext_vector_type(8))) short bf16x8;
typedef __attribute__((ext_vector_type(4))) float f32x4;
typedef __attribute__((ext_vector_type(4))) unsigned short u16x4;

#define QN    2048
#define BSZ   128
#define TMAXK 128
#define STEPF 0.01f
#define NEWTON_ITERS 46

__device__ __forceinline__ u16 f2bf(float f){
  unsigned u = __float_as_uint(f);
  u += 0x7fffu + ((u >> 16) & 1u);          // round-to-nearest-even
  return (u16)(u >> 16);
}
__device__ __forceinline__ float bf2f(u16 h){
  return __uint_as_float(((unsigned)h) << 16);
}

// ============================ preprocessing ============================

// alpha[q] = ||P_q||_1 * ||P_q||_inf  >= sigma_max(P_q)^2
__global__ __launch_bounds__(256) void alpha_k(const float* __restrict__ P, float* __restrict__ alpha){
  int q = blockIdx.x, i = threadIdx.x;
  const float* Pb = P + (size_t)(q << 8) * QN + (q << 8);
  float rs = 0.f, cs = 0.f;
  for (int c = 0; c < 256; ++c){
    rs += fabsf(Pb[(size_t)i * QN + c]);
    cs += fabsf(Pb[(size_t)c * QN + i]);
  }
  __shared__ float red[256];
  red[i] = rs; __syncthreads();
  for (int o = 128; o > 0; o >>= 1){ if (i < o) red[i] = fmaxf(red[i], red[i+o]); __syncthreads(); }
  float mr = red[0];
  __syncthreads();
  red[i] = cs; __syncthreads();
  for (int o = 128; o > 0; o >>= 1){ if (i < o) red[i] = fmaxf(red[i], red[i+o]); __syncthreads(); }
  if (i == 0) alpha[q] = mr * red[0];
}

// V0 = P_q^T / alpha[q]
__global__ __launch_bounds__(256) void initV_k(const float* __restrict__ P, const float* __restrict__ alpha, float* __restrict__ V){
  int idx = blockIdx.x * 256 + threadIdx.x;
  int q = idx >> 16, rc = idx & 65535;
  int r = rc >> 8, c = rc & 255;
  V[idx] = P[(size_t)((q << 8) + c) * QN + (q << 8) + r] / alpha[q];
}

// T[q] = P_q @ V[q]
__global__ __launch_bounds__(256) void newton_T_k(const float* __restrict__ P, const float* __restrict__ Vin, float* __restrict__ Tm){
  int q = blockIdx.x >> 4;
  int tl = blockIdx.x & 15;
  int rb = (tl >> 2) << 6, cb = (tl & 3) << 6;
  const float* Ab = P + (size_t)(q << 8) * QN + (q << 8);
  const float* Bb = Vin + (q << 16);
  __shared__ float Asm[16][68];
  __shared__ float Bsm[16][68];
  int tid = threadIdx.x, ty = tid >> 4, tx = tid & 15;
  float acc[4][4];
#pragma unroll
  for (int i = 0; i < 4; i++)
#pragma unroll
    for (int j = 0; j < 4; j++) acc[i][j] = 0.f;
  int ar = tid >> 2, ak = (tid & 3) << 2;
  int bc = tid & 63, bk = tid >> 6;
  for (int kb = 0; kb < 256; kb += 16){
    f32x4 av = *(const f32x4*)(Ab + (size_t)(rb + ar) * QN + kb + ak);
    float b0 = Bb[(size_t)(kb + bk     ) * 256 + cb + bc];
    float b1 = Bb[(size_t)(kb + bk +  4) * 256 + cb + bc];
    float b2 = Bb[(size_t)(kb + bk +  8) * 256 + cb + bc];
    float b3 = Bb[(size_t)(kb + bk + 12) * 256 + cb + bc];
    __syncthreads();
    Asm[ak+0][ar] = av.x; Asm[ak+1][ar] = av.y; Asm[ak+2][ar] = av.z; Asm[ak+3][ar] = av.w;
    Bsm[bk   ][bc] = b0;  Bsm[bk+ 4][bc] = b1;  Bsm[bk+ 8][bc] = b2;  Bsm[bk+12][bc] = b3;
    __syncthreads();
#pragma unroll
    for (int kk = 0; kk < 16; kk++){
      f32x4 a = *(const f32x4*)&Asm[kk][ty << 2];
      f32x4 b = *(const f32x4*)&Bsm[kk][tx << 2];
#pragma unroll
      for (int i = 0; i < 4; i++)
#pragma unroll
        for (int j = 0; j < 4; j++) acc[i][j] += a[i] * b[j];
    }
  }
  float* Ob = Tm + (q << 16);
#pragma unroll
  for (int i = 0; i < 4; i++){
    f32x4 o; o.x = acc[i][0]; o.y = acc[i][1]; o.z = acc[i][2]; o.w = acc[i][3];
    *(f32x4*)(Ob + (size_t)(rb + (ty << 2) + i) * 256 + cb + (tx << 2)) = o;
  }
}

// Vout[q] = 2*Vin[q] - Vin[q] @ T[q]
__global__ __launch_bounds__(256) void newton_V_k(const float* __restrict__ Vin, const float* __restrict__ Tm, float* __restrict__ Vout){
  int q = blockIdx.x >> 4;
  int tl = blockIdx.x & 15;
  int rb = (tl >> 2) << 6, cb = (tl & 3) << 6;
  const float* Ab = Vin + (q << 16);
  const float* Bb = Tm + (q << 16);
  __shared__ float Asm[16][68];
  __shared__ float Bsm[16][68];
  int tid = threadIdx.x, ty = tid >> 4, tx = tid & 15;
  float acc[4][4];
#pragma unroll
  for (int i = 0; i < 4; i++)
#pragma unroll
    for (int j = 0; j < 4; j++) acc[i][j] = 0.f;
  int ar = tid >> 2, ak = (tid & 3) << 2;
  int bc = tid & 63, bk = tid >> 6;
  for (int kb = 0; kb < 256; kb += 16){
    f32x4 av = *(const f32x4*)(Ab + (size_t)(rb + ar) * 256 + kb + ak);
    float b0 = Bb[(size_t)(kb + bk     ) * 256 + cb + bc];
    float b1 = Bb[(size_t)(kb + bk +  4) * 256 + cb + bc];
    float b2 = Bb[(size_t)(kb + bk +  8) * 256 + cb + bc];
    float b3 = Bb[(size_t)(kb + bk + 12) * 256 + cb + bc];
    __syncthreads();
    Asm[ak+0][ar] = av.x; Asm[ak+1][ar] = av.y; Asm[ak+2][ar] = av.z; Asm[ak+3][ar] = av.w;
    Bsm[bk   ][bc] = b0;  Bsm[bk+ 4][bc] = b1;  Bsm[bk+ 8][bc] = b2;  Bsm[bk+12][bc] = b3;
    __syncthreads();
#pragma unroll
    for (int kk = 0; kk < 16; kk++){
      f32x4 a = *(const f32x4*)&Asm[kk][ty << 2];
      f32x4 b = *(const f32x4*)&Bsm[kk][tx << 2];
#pragma unroll
      for (int i = 0; i < 4; i++)
#pragma unroll
        for (int j = 0; j < 4; j++) acc[i][j] += a[i] * b[j];
    }
  }
  float* Ob = Vout + (q << 16);
#pragma unroll
  for (int i = 0; i < 4; i++){
    f32x4 vo = *(const f32x4*)(Ab + (size_t)(rb + (ty << 2) + i) * 256 + cb + (tx << 2));
    f32x4 o;
    o.x = 2.f*vo.x - acc[i][0]; o.y = 2.f*vo.y - acc[i][1];
    o.z = 2.f*vo.z - acc[i][2]; o.w = 2.f*vo.w - acc[i][3];
    *(f32x4*)(Ob + (size_t)(rb + (ty << 2) + i) * 256 + cb + (tx << 2)) = o;
  }
}

// Ymat[:, Bj] = Wm[Bj,:]^T @ P_j
__global__ __launch_bounds__(256) void build_Y_k(const float* __restrict__ W, const float* __restrict__ P, float* __restrict__ Ymat){
  int j  = blockIdx.x >> 7;
  int rt = (blockIdx.x >> 2) & 31;
  int ct = blockIdx.x & 3;
  int rb = rt << 6, cb = ct << 6, jb = j << 8;
  int tid = threadIdx.x, ty = tid >> 4, tx = tid & 15;
  if ((rt >> 2) == j){
#pragma unroll
    for (int i = 0; i < 4; i++){
      f32x4 z = {0.f, 0.f, 0.f, 0.f};
      *(f32x4*)(Ymat + (size_t)(rb + (ty << 2) + i) * QN + jb + cb + (tx << 2)) = z;
    }
    return;
  }
  __shared__ float Asm[16][68];
  __shared__ float Bsm[16][68];
  float acc[4][4];
#pragma unroll
  for (int i = 0; i < 4; i++)
#pragma unroll
    for (int j2 = 0; j2 < 4; j2++) acc[i][j2] = 0.f;
  int sr = tid & 63, sk = tid >> 6;
  for (int kb = 0; kb < 256; kb += 16){
    float a0 = W[(size_t)(jb + kb + sk     ) * QN + rb + sr];
    float a1 = W[(size_t)(jb + kb + sk +  4) * QN + rb + sr];
    float a2 = W[(size_t)(jb + kb + sk +  8) * QN + rb + sr];
    float a3 = W[(size_t)(jb + kb + sk + 12) * QN + rb + sr];
    float b0 = P[(size_t)(jb + kb + sk     ) * QN + jb + cb + sr];
    float b1 = P[(size_t)(jb + kb + sk +  4) * QN + jb + cb + sr];
    float b2 = P[(size_t)(jb + kb + sk +  8) * QN + jb + cb + sr];
    float b3 = P[(size_t)(jb + kb + sk + 12) * QN + jb + cb + sr];
    __syncthreads();
    Asm[sk   ][sr] = a0; Asm[sk+ 4][sr] = a1; Asm[sk+ 8][sr] = a2; Asm[sk+12][sr] = a3;
    Bsm[sk   ][sr] = b0; Bsm[sk+ 4][sr] = b1; Bsm[sk+ 8][sr] = b2; Bsm[sk+12][sr] = b3;
    __syncthreads();
#pragma unroll
    for (int kk = 0; kk < 16; kk++){
      f32x4 a = *(const f32x4*)&Asm[kk][ty << 2];
      f32x4 b = *(const f32x4*)&Bsm[kk][tx << 2];
#pragma unroll
      for (int i = 0; i < 4; i++)
#pragma unroll
        for (int j2 = 0; j2 < 4; j2++) acc[i][j2] += a[i] * b[j2];
    }
  }
#pragma unroll
  for (int i = 0; i < 4; i++){
    f32x4 o; o.x = acc[i][0]; o.y = acc[i][1]; o.z = acc[i][2]; o.w = acc[i][3];
    *(f32x4*)(Ymat + (size_t)(rb + (ty << 2) + i) * QN + jb + cb + (tx << 2)) = o;
  }
}

// Z[Bi,:] = V_i @ Ymat[Bi,:];  M = A + Wm - Z; bf16 hi->C1, lo->C2 (cols 0..2047)
__global__ __launch_bounds__(256) void build_C_k(const float* __restrict__ Vfin, const float* __restrict__ Ymat,
                                                 const float* __restrict__ Ain, const float* __restrict__ W,
                                                 u16* __restrict__ C1, u16* __restrict__ C2){
  int ib = blockIdx.x >> 7;
  int rest = blockIdx.x & 127;
  int rt = rest >> 5, ct = rest & 31;
  int rb = rt << 6, cb = ct << 6;
  const float* Ab = Vfin + (ib << 16);
  __shared__ float Asm[16][68];
  __shared__ float Bsm[16][68];
  int tid = threadIdx.x, ty = tid >> 4, tx = tid & 15;
  float acc[4][4];
#pragma unroll
  for (int i = 0; i < 4; i++)
#pragma unroll
    for (int j = 0; j < 4; j++) acc[i][j] = 0.f;
  int ar = tid >> 2, ak = (tid & 3) << 2;
  int bc = tid & 63, bk = tid >> 6;
  for (int kb = 0; kb < 256; kb += 16){
    f32x4 av = *(const f32x4*)(Ab + (size_t)(rb + ar) * 256 + kb + ak);
    float b0 = Ymat[(size_t)((ib << 8) + kb + bk     ) * QN + cb + bc];
    float b1 = Ymat[(size_t)((ib << 8) + kb + bk +  4) * QN + cb + bc];
    float b2 = Ymat[(size_t)((ib << 8) + kb + bk +  8) * QN + cb + bc];
    float b3 = Ymat[(size_t)((ib << 8) + kb + bk + 12) * QN + cb + bc];
    __syncthreads();
    Asm[ak+0][ar] = av.x; Asm[ak+1][ar] = av.y; Asm[ak+2][ar] = av.z; Asm[ak+3][ar] = av.w;
    Bsm[bk   ][bc] = b0;  Bsm[bk+ 4][bc] = b1;  Bsm[bk+ 8][bc] = b2;  Bsm[bk+12][bc] = b3;
    __syncthreads();
#pragma unroll
    for (int kk = 0; kk < 16; kk++){
      f32x4 a = *(const f32x4*)&Asm[kk][ty << 2];
      f32x4 b = *(const f32x4*)&Bsm[kk][tx << 2];
#pragma unroll
      for (int i = 0; i < 4; i++)
#pragma unroll
        for (int j = 0; j < 4; j++) acc[i][j] += a[i] * b[j];
    }
  }
#pragma unroll
  for (int i = 0; i < 4; i++){
    int row = (ib << 8) + rb + (ty << 2) + i;
#pragma unroll
    for (int j = 0; j < 4; j++){
      int col = cb + (tx << 2) + j;
      float wv = ((row >> 8) == (col >> 8)) ? 0.f : W[(size_t)row * QN + col];
      float m = Ain[(size_t)row * QN + col] + wv - acc[i][j];
      u16 hi = f2bf(m);
      u16 lo = f2bf(m - bf2f(hi));
      C1[((size_t)row << 12) + col] = hi;
      C2[((size_t)row << 12) + col] = lo;
    }
  }
}

// B matrix -> bf16 hi/lo into C1/C2 (cols 2048..4095)
__global__ __launch_bounds__(256) void split_B_k(const float* __restrict__ Bin, u16* __restrict__ C1, u16* __restrict__ C2){
  int idx = blockIdx.x * 256 + threadIdx.x;
  int r = idx >> 11, c = idx & 2047;
  float v = Bin[idx];
  u16 hi = f2bf(v);
  u16 lo = f2bf(v - bf2f(hi));
  C1[((size_t)r << 12) + 2048 + c] = hi;
  C2[((size_t)r << 12) + 2048 + c] = lo;
}

// Xf = X0; Yst = [bf16(X0) | bf16(relu X0)]; out[:,0,:] = X0
__global__ __launch_bounds__(256) void init_state_k(const float* __restrict__ X0, float* __restrict__ Xf,
                                                    u16* __restrict__ Yst, float* __restrict__ out){
  int idx = blockIdx.x * 256 + threadIdx.x;
  int bs = idx >> 11, qn = idx & 2047;
  float x = X0[idx];
  Xf[idx] = x;
  Yst[((size_t)bs << 12) + qn] = f2bf(x);
  Yst[((size_t)bs << 12) + 2048 + qn] = f2bf(fmaxf(x, 0.f));
  out[((size_t)bs * TMAXK) * QN + qn] = x;
}

// ============================ main loop ============================

// Split-K partial GEMM, hi+lo panels. 512 blocks = 64 rowgroups (32 rows) x 8 k-slices (512 k).
// slice = blockIdx&7 -> fixed XCD (round-robin dispatch) -> the 4 MB C-slice (both panels)
// stays L2-resident across all 127 steps. part written NT (no L2 pollution).
__global__ __launch_bounds__(256) void step_gemm_k(const u16* __restrict__ C1, const u16* __restrict__ C2,
                                                   const u16* __restrict__ Yst, float* __restrict__ part){
  __shared__ __align__(16) char lds[65536];  // [2 panels][32 r][512 k] bf16, XOR-swizzled
  int tid = threadIdx.x;
  int b = blockIdx.x;
  int s = b & 7, rg = b >> 3;
  int k0 = s << 9;
  // stage C tiles (reg->LDS, swizzled)
  for (int it = 0; it < 16; ++it){
    int e = it * 256 + tid;                 // [0,4096): 8 bf16 each
    const u16* src = (e < 2048) ? C1 : C2;  // uniform per it
    int el = e & 2047;
    int r = el >> 6;                        // 0..31
    int k8 = (el & 63) << 3;                // 0..504
    bf16x8 v = *(const bf16x8*)(src + ((size_t)((rg << 5) + r) << 12) + k0 + k8);
    int addr = ((e >> 11) << 15) + (((r << 10) + (k8 << 1)) ^ ((r & 7) << 4));
    *(bf16x8*)(lds + addr) = v;
  }
  __syncthreads();
  int w = tid >> 6, l = tid & 63;
  int lo16 = l & 15, hi = l >> 4;
  f32x4 acc[2][2];
#pragma unroll
  for (int m = 0; m < 2; m++)
#pragma unroll
    for (int n = 0; n < 2; n++) acc[m][n] = (f32x4){0.f, 0.f, 0.f, 0.f};
  const u16* yb = Yst + ((size_t)((w << 5) + lo16) << 12) + k0 + (hi << 3);
#pragma unroll
  for (int kt = 0; kt < 16; ++kt){
    bf16x8 b0 = *(const bf16x8*)(yb + (kt << 5));
    bf16x8 b1 = *(const bf16x8*)(yb + (16 << 12) + (kt << 5));   // +16 bs rows
    int kb2 = ((kt << 5) + (hi << 3)) << 1;
#pragma unroll
    for (int m = 0; m < 2; m++){
      int row = (m << 4) + lo16;
      int ba = ((row << 10) + kb2) ^ ((row & 7) << 4);
      bf16x8 a1 = *(const bf16x8*)(lds + ba);
      bf16x8 a2 = *(const bf16x8*)(lds + 32768 + ba);
      acc[m][0] = __builtin_amdgcn_mfma_f32_16x16x32_bf16(a1, b0, acc[m][0], 0, 0, 0);
      acc[m][0] = __builtin_amdgcn_mfma_f32_16x16x32_bf16(a2, b0, acc[m][0], 0, 0, 0);
      acc[m][1] = __builtin_amdgcn_mfma_f32_16x16x32_bf16(a1, b1, acc[m][1], 0, 0, 0);
      acc[m][1] = __builtin_amdgcn_mfma_f32_16x16x32_bf16(a2, b1, acc[m][1], 0, 0, 0);
    }
  }
  // part[s][bs][row]; D-frag: col(=bs)=lane&15, row=(lane>>4)*4+reg
#pragma unroll
  for (int m = 0; m < 2; m++)
#pragma unroll
    for (int n = 0; n < 2; n++){
      int bs = (w << 5) + (n << 4) + lo16;
      int row = (rg << 5) + (m << 4) + (hi << 2);
      __builtin_nontemporal_store(acc[m][n], (f32x4*)(part + ((size_t)((s << 7) + bs) << 11) + row));
    }
}

// Reduce 8 partials, X += STEP*(U + b), emit out[:,t,:] and next bf16 Y state
__global__ __launch_bounds__(256) void step_update_k(const float* __restrict__ part, float* __restrict__ Xf,
                                                     const float* __restrict__ bx, u16* __restrict__ Yst,
                                                     float* __restrict__ out, int t){
  int tid = blockIdx.x * 256 + threadIdx.x;   // 65536 threads x 4 elems
  int bs = tid >> 9;
  int row = (tid & 511) << 2;
  size_t base = ((size_t)bs << 11) + row;
  f32x4 u = {0.f, 0.f, 0.f, 0.f};
#pragma unroll
  for (int s = 0; s < 8; s++){
    f32x4 p = __builtin_nontemporal_load((const f32x4*)(part + ((size_t)((s << 7) + bs) << 11) + row));
    u += p;
  }
  f32x4 x = *(const f32x4*)(Xf + base);
  f32x4 b = *(const f32x4*)(bx + row);
  f32x4 xn = x + STEPF * (u + b);
  *(f32x4*)(Xf + base) = xn;
  __builtin_nontemporal_store(xn, (f32x4*)(out + ((size_t)((bs << 7) + t) << 11) + row));
  u16x4 hv, rv;
  hv.x = f2bf(xn.x); hv.y = f2bf(xn.y); hv.z = f2bf(xn.z); hv.w = f2bf(xn.w);
  rv.x = f2bf(fmaxf(xn.x, 0.f)); rv.y = f2bf(fmaxf(xn.y, 0.f));
  rv.z = f2bf(fmaxf(xn.z, 0.f)); rv.w = f2bf(fmaxf(xn.w, 0.f));
  *(u16x4*)(Yst + ((size_t)bs << 12) + row) = hv;
  *(u16x4*)(Yst + ((size_t)bs << 12) + 2048 + row) = rv;
}

// ============================ host ============================

extern "C" void kernel_launch(void* const* d_in, const int* in_sizes, int n_in,
                              void* d_out, int out_size, void* d_ws, size_t ws_size,
                              hipStream_t stream){
  (void)in_sizes; (void)n_in; (void)out_size; (void)ws_size;
  const float* X0  = (const float*)d_in[0];
  const float* Ain = (const float*)d_in[1];
  const float* Bin = (const float*)d_in[2];
  const float* Win = (const float*)d_in[3];
  const float* Pin = (const float*)d_in[4];
  const float* bx  = (const float*)d_in[5];
  float* out = (float*)d_out;
  char* ws = (char*)d_ws;
  const size_t MB = 1u << 20;

  u16*   C1    = (u16*)(ws);               // 16 MB [2048][4096] bf16 = [Mh|Bh]
  u16*   C2    = (u16*)(ws + 16*MB);       // 16 MB [Ml|Bl]
  float* Xf    = (float*)(ws + 32*MB);     // 1 MB  [128][2048] f32 state
  u16*   Yst   = (u16*)(ws + 33*MB);       // 1 MB  [128][4096] bf16 [X|relu X]
  float* Ymat  = (float*)(ws + 34*MB);     // 16 MB (preproc)  -- aliased with:
  float* part  = (float*)(ws + 34*MB);     // 8 MB [8][128][2048] f32 partials (main loop)
  float* Vb0   = (float*)(ws + 50*MB);     // 2 MB  8x256x256
  float* Vb1   = (float*)(ws + 52*MB);     // 2 MB
  float* Tm    = (float*)(ws + 54*MB);     // 2 MB
  float* alpha = (float*)(ws + 56*MB);     // 32 B

  // --- preprocessing: blockwise P^-1 via Newton-Schulz ---
  alpha_k<<<8, 256, 0, stream>>>(Pin, alpha);
  initV_k<<<2048, 256, 0, stream>>>(Pin, alpha, Vb0);
  float* Vc = Vb0; float* Vo = Vb1;
  for (int it = 0; it < NEWTON_ITERS; ++it){
    newton_T_k<<<128, 256, 0, stream>>>(Pin, Vc, Tm);
    newton_V_k<<<128, 256, 0, stream>>>(Vc, Tm, Vo);
    float* tmp = Vc; Vc = Vo; Vo = tmp;
  }
  // --- M = A + Wm - P^-1 Wm^T P -> bf16 hi/lo; B -> bf16 hi/lo ---
  build_Y_k<<<1024, 256, 0, stream>>>(Win, Pin, Ymat);
  build_C_k<<<1024, 256, 0, stream>>>(Vc, Ymat, Ain, Win, C1, C2);
  split_B_k<<<16384, 256, 0, stream>>>(Bin, C1, C2);
  init_state_k<<<1024, 256, 0, stream>>>(X0, Xf, Yst, out);

  // --- 127 sequential steps ---
  for (int t = 1; t < TMAXK; ++t){
    step_gemm_k<<<512, 256, 0, stream>>>(C1, C2, Yst, part);
    step_update_k<<<256, 256, 0, stream>>>(part, Xf, bx, Yst, out, t);
  }
}